// Round 6
// baseline (168.286 us; speedup 1.0000x reference)
//
#include <hip/hip_runtime.h>
#include <hip/hip_bf16.h>
#include <math.h>

#define T_NODES 8192
#define BGRAPHS 16
#define CDIM 128
#define HEADS 4
#define DHEAD 32
#define KNN 16

// ---------------------------------------------------------------------------
// Kernel 1: segment counts/starts from sorted batch ids
// ---------------------------------------------------------------------------
__global__ __launch_bounds__(256) void k_counts(const int* __restrict__ batch,
                                                int* __restrict__ starts,
                                                int* __restrict__ counts) {
    __shared__ int cnt[BGRAPHS];
    int tid = threadIdx.x;
    if (tid < BGRAPHS) cnt[tid] = 0;
    __syncthreads();
    for (int i = tid; i < T_NODES; i += 256) {
        atomicAdd(&cnt[batch[i]], 1);
    }
    __syncthreads();
    if (tid == 0) {
        int s = 0;
        for (int b = 0; b < BGRAPHS; ++b) {
            starts[b] = s;
            counts[b] = cnt[b];
            s += cnt[b];
        }
    }
}

// ---------------------------------------------------------------------------
// Kernel 2: node embedding f0 = x @ emb_W + emb_b   [T,128]
// ---------------------------------------------------------------------------
__global__ __launch_bounds__(256) void k_embed(const float* __restrict__ x,
                                               const float* __restrict__ embW,
                                               const float* __restrict__ embb,
                                               float* __restrict__ f0) {
    int gid = blockIdx.x * 256 + threadIdx.x;
    int t = gid >> 7;
    int c = gid & 127;
    float acc = embb[c];
#pragma unroll
    for (int i = 0; i < 11; ++i) {
        acc += x[t * 11 + i] * embW[i * CDIM + c];
    }
    f0[t * CDIM + c] = acc;
}

// ---------------------------------------------------------------------------
// Kernel 3: kNN. One wave (64 lanes) per node; lane holds 16 candidate slots
// (j = lane + sl*64, coalesced). Each lane Batcher-sorts its 16 (d2, slot)
// pairs once; then 16 rounds of {d2-only fmin wave reduce -> ballot winner ->
// winner shifts}. Writes packed dird float4 {dx,dy,dz,dist} per (t,k).
// ---------------------------------------------------------------------------
__global__ __launch_bounds__(256) void k_knn(const float* __restrict__ pos,
                                             const int* __restrict__ batch,
                                             const int* __restrict__ starts,
                                             const int* __restrict__ counts,
                                             int* __restrict__ nbr,
                                             float4* __restrict__ dird) {
    int wave = threadIdx.x >> 6;
    int lane = threadIdx.x & 63;
    int t = blockIdx.x * 4 + wave;
    if (t >= T_NODES) return;

    int b = batch[t];
    int s = starts[b];
    int n = counts[b];

    float px = pos[t * 3 + 0];
    float py = pos[t * 3 + 1];
    float pz = pos[t * 3 + 2];

    float sd[16];
    int ss[16];
#pragma unroll
    for (int sl = 0; sl < 16; ++sl) {
        int j = lane + sl * 64;
        float d2 = 1e30f;
        if (j < n) {
            int jj = s + j;
            float dx = px - pos[jj * 3 + 0];
            float dy = py - pos[jj * 3 + 1];
            float dz = pz - pos[jj * 3 + 2];
            d2 = dx * dx + dy * dy + dz * dz;
        }
        sd[sl] = d2;
        ss[sl] = sl;
    }

    // Batcher odd-even mergesort of 16 (d2, slot) pairs; ascending d2.
#pragma unroll
    for (int p = 1; p < 16; p <<= 1) {
#pragma unroll
        for (int k = p; k >= 1; k >>= 1) {
#pragma unroll
            for (int j = (k & (p - 1)); j + k < 16; j += 2 * k) {
#pragma unroll
                for (int i = 0; i < k; ++i) {
                    if (i + j + k < 16 && ((i + j) / (2 * p)) == ((i + j + k) / (2 * p))) {
                        int a = i + j, c2 = i + j + k;
                        bool sw = sd[a] > sd[c2];
                        float td = sd[a];
                        int ts = ss[a];
                        sd[a] = sw ? sd[c2] : sd[a];
                        ss[a] = sw ? ss[c2] : ss[a];
                        sd[c2] = sw ? td : sd[c2];
                        ss[c2] = sw ? ts : ss[c2];
                    }
                }
            }
        }
    }

    float resd = 1e30f;
    int resj = -1;

#pragma unroll
    for (int r = 0; r < KNN; ++r) {
        float rd = sd[0];
#pragma unroll
        for (int off = 32; off >= 1; off >>= 1) {
            rd = fminf(rd, __shfl_xor(rd, off));
        }
        unsigned long long mask = __ballot(sd[0] == rd);
        int wl = (int)__builtin_ctzll(mask);
        int ws = __shfl(ss[0], wl);
        if (lane == r) { resd = rd; resj = wl + ws * 64; }
        if (lane == wl) {
#pragma unroll
            for (int i = 0; i < 15; ++i) { sd[i] = sd[i + 1]; ss[i] = ss[i + 1]; }
            sd[15] = 1e30f;
        }
    }

    if (lane < KNN) {
        bool valid = (resd < 1e29f);
        int jf = valid ? (s + resj) : -1;
        nbr[t * KNN + lane] = jf;
        float dd = sqrtf(resd + 1e-6f);
        float dx = 0.f, dy = 0.f, dz = 0.f;
        if (valid) {
            float inv = 1.f / dd;
            dx = (px - pos[jf * 3 + 0]) * inv;
            dy = (py - pos[jf * 3 + 1]) * inv;
            dz = (pz - pos[jf * 3 + 2]) * inv;
        }
        float4 v;
        v.x = dx; v.y = dy; v.z = dz; v.w = dd;
        dird[t * KNN + lane] = v;
    }
}

// ---------------------------------------------------------------------------
// Kernel 4: fused QKV projection. qkvv[t, 0:512] = f0[t,:] @ [Wq|Wk|Wv0|Wv1]
// ---------------------------------------------------------------------------
__global__ __launch_bounds__(256) void k_qkv(const float* __restrict__ f0,
                                             const float* __restrict__ Wq,
                                             const float* __restrict__ Wk,
                                             const float* __restrict__ Wv0,
                                             const float* __restrict__ Wv1,
                                             float* __restrict__ qkvv) {
    __shared__ float sf[16][CDIM];
    int t0 = blockIdx.x * 16;
    int tid = threadIdx.x;
    for (int i = tid; i < 16 * CDIM; i += 256) {
        sf[i >> 7][i & 127] = f0[(t0 + (i >> 7)) * CDIM + (i & 127)];
    }
    __syncthreads();

    const float* W1 = (tid < 128) ? Wq : Wk;    // wave-uniform
    const float* W2 = (tid < 128) ? Wv0 : Wv1;  // wave-uniform
    int col = tid & 127;

    float acc1[16], acc2[16];
#pragma unroll
    for (int nn = 0; nn < 16; ++nn) { acc1[nn] = 0.f; acc2[nn] = 0.f; }

    for (int c0 = 0; c0 < CDIM; c0 += 8) {
        float w1[8], w2[8];
#pragma unroll
        for (int cc = 0; cc < 8; ++cc) {
            w1[cc] = W1[(c0 + cc) * CDIM + col];
            w2[cc] = W2[(c0 + cc) * CDIM + col];
        }
#pragma unroll
        for (int nn = 0; nn < 16; ++nn) {
            float4 fa = *(const float4*)&sf[nn][c0];
            float4 fb = *(const float4*)&sf[nn][c0 + 4];
            acc1[nn] += fa.x * w1[0] + fa.y * w1[1] + fa.z * w1[2] + fa.w * w1[3]
                      + fb.x * w1[4] + fb.y * w1[5] + fb.z * w1[6] + fb.w * w1[7];
            acc2[nn] += fa.x * w2[0] + fa.y * w2[1] + fa.z * w2[2] + fa.w * w2[3]
                      + fb.x * w2[4] + fb.y * w2[5] + fb.z * w2[6] + fb.w * w2[7];
        }
    }
#pragma unroll
    for (int nn = 0; nn < 16; ++nn) {
        qkvv[(size_t)(t0 + nn) * 512 + tid] = acc1[nn];
        qkvv[(size_t)(t0 + nn) * 512 + 256 + tid] = acc2[nn];
    }
}

// ---------------------------------------------------------------------------
// Kernel 5: kNN attention. 2 nodes per 256-thread block; XCD-swizzled so each
// XCD covers a contiguous 1024-node range (gather working set ~2MB -> L2-fit).
// out0 [T,128]; out1 planar [3][T,128].
// ---------------------------------------------------------------------------
__global__ __launch_bounds__(256) void k_attn(const float* __restrict__ qkvv,
                                              const int* __restrict__ nbr,
                                              const float4* __restrict__ dird,
                                              const float* __restrict__ dist_scale,
                                              float* __restrict__ out0,
                                              float* __restrict__ out1) {
    int bid = blockIdx.x;
    // bijective swizzle over 4096 blocks: chunk = bid&7 -> contiguous 512 blocks
    int swz = (bid & 7) * (T_NODES / 16) + (bid >> 3);
    int t = swz * 2 + (threadIdx.x >> 7);
    int c = threadIdx.x & 127;
    int h = c >> 5;

    float q = qkvv[(size_t)t * 512 + c];
    float xs = dist_scale[h];
    float sp = (xs > 20.f) ? xs : log1pf(expf(xs));  // softplus

    // neighbor ids: 4 x int4 broadcast loads
    int js[KNN];
    {
        const int4* nb4 = (const int4*)&nbr[t * KNN];
#pragma unroll
        for (int k4 = 0; k4 < 4; ++k4) {
            int4 v = nb4[k4];
            js[k4 * 4 + 0] = v.x;
            js[k4 * 4 + 1] = v.y;
            js[k4 * 4 + 2] = v.z;
            js[k4 * 4 + 3] = v.w;
        }
    }
    // packed direction+dist
    float4 dv[KNN];
#pragma unroll
    for (int k = 0; k < KNN; ++k) dv[k] = dird[t * KNN + k];

    float lg[KNN];
#pragma unroll
    for (int k = 0; k < KNN; ++k) {
        int j = js[k];
        float kv = (j >= 0) ? qkvv[(size_t)j * 512 + 128 + c] : 0.f;
        float p = q * kv;
        p += __shfl_xor(p, 16);
        p += __shfl_xor(p, 8);
        p += __shfl_xor(p, 4);
        p += __shfl_xor(p, 2);
        p += __shfl_xor(p, 1);
        float l = -1e30f;
        if (j >= 0) l = p * 0.17677669529663687f - sp * dv[k].w;
        lg[k] = l;
    }

    float m = lg[0];
#pragma unroll
    for (int k = 1; k < KNN; ++k) m = fmaxf(m, lg[k]);
    float ssum = 0.f;
    float at[KNN];
#pragma unroll
    for (int k = 0; k < KNN; ++k) {
        float e = expf(lg[k] - m);
        at[k] = e;
        ssum += e;
    }
    float rs = 1.f / ssum;

    float o0 = 0.f, o1x = 0.f, o1y = 0.f, o1z = 0.f;
#pragma unroll
    for (int k = 0; k < KNN; ++k) {
        int j = js[k];
        if (j >= 0) {
            float a = at[k] * rs;
            float v0 = qkvv[(size_t)j * 512 + 256 + c];
            float v1 = qkvv[(size_t)j * 512 + 384 + c];
            o0 += a * v0;
            float av1 = a * v1;
            o1x += av1 * dv[k].x;
            o1y += av1 * dv[k].y;
            o1z += av1 * dv[k].z;
        }
    }
    out0[(size_t)t * CDIM + c] = o0;
    out1[0 * (size_t)T_NODES * CDIM + (size_t)t * CDIM + c] = o1x;
    out1[1 * (size_t)T_NODES * CDIM + (size_t)t * CDIM + c] = o1y;
    out1[2 * (size_t)T_NODES * CDIM + (size_t)t * CDIM + c] = o1z;
}

// ---------------------------------------------------------------------------
// Kernel 6: f1 = out1 @ Wo1 (per xyz), inv = ||f1||, f0_out = f0 + out0@Wo0 + inv@Wg
// LDS-staged, register-blocked. 8 nodes/block, 256 threads.
// ---------------------------------------------------------------------------
#define MIXN 8
__global__ __launch_bounds__(256) void k_mix(const float* __restrict__ f0,
                                             const float* __restrict__ out0,
                                             const float* __restrict__ out1,
                                             const float* __restrict__ Wo1,
                                             const float* __restrict__ Wo0,
                                             const float* __restrict__ Wg,
                                             float* __restrict__ f0out) {
    __shared__ float s_out1[3][MIXN][CDIM];  // 12 KB
    __shared__ float s_out0[MIXN][CDIM];     //  4 KB
    __shared__ float s_inv[MIXN][CDIM];      //  4 KB
    int tid = threadIdx.x;
    int t0 = blockIdx.x * MIXN;

    {
        const float4* p1 = (const float4*)out1;
        float4* s1 = (float4*)s_out1;
        for (int i = tid; i < 3 * MIXN * 32; i += 256) {
            int cp = i >> 8;
            int rem = i & 255;
            int nn = rem >> 5;
            int c4 = rem & 31;
            s1[i] = p1[(size_t)cp * (T_NODES * 32) + (size_t)(t0 + nn) * 32 + c4];
        }
        const float4* p0 = (const float4*)out0;
        float4* s0 = (float4*)s_out0;
        {
            int i = tid;
            int nn = i >> 5, c4 = i & 31;
            s0[i] = p0[(size_t)(t0 + nn) * 32 + c4];
        }
    }
    __syncthreads();

    int d0 = tid & 63;
    int g = tid >> 6;  // 0..3; nodes g and g+4

    float f1a[2][3][2];
#pragma unroll
    for (int ni = 0; ni < 2; ++ni)
#pragma unroll
        for (int cp = 0; cp < 3; ++cp) {
            f1a[ni][cp][0] = 0.f;
            f1a[ni][cp][1] = 0.f;
        }

    for (int c0 = 0; c0 < CDIM; c0 += 4) {
        float w[4][2];
#pragma unroll
        for (int cc = 0; cc < 4; ++cc) {
            w[cc][0] = Wo1[(c0 + cc) * CDIM + d0];
            w[cc][1] = Wo1[(c0 + cc) * CDIM + d0 + 64];
        }
#pragma unroll
        for (int ni = 0; ni < 2; ++ni) {
            int nn = g + ni * 4;
#pragma unroll
            for (int cp = 0; cp < 3; ++cp) {
                float4 v = *(const float4*)&s_out1[cp][nn][c0];
                f1a[ni][cp][0] += v.x * w[0][0] + v.y * w[1][0] + v.z * w[2][0] + v.w * w[3][0];
                f1a[ni][cp][1] += v.x * w[0][1] + v.y * w[1][1] + v.z * w[2][1] + v.w * w[3][1];
            }
        }
    }
#pragma unroll
    for (int ni = 0; ni < 2; ++ni) {
        int nn = g + ni * 4;
        s_inv[nn][d0] = sqrtf(f1a[ni][0][0] * f1a[ni][0][0] + f1a[ni][1][0] * f1a[ni][1][0]
                            + f1a[ni][2][0] * f1a[ni][2][0] + 1e-6f);
        s_inv[nn][d0 + 64] = sqrtf(f1a[ni][0][1] * f1a[ni][0][1] + f1a[ni][1][1] * f1a[ni][1][1]
                                 + f1a[ni][2][1] * f1a[ni][2][1] + 1e-6f);
    }
    __syncthreads();

    float r[2][2];
#pragma unroll
    for (int ni = 0; ni < 2; ++ni) {
        int t = t0 + g + ni * 4;
        r[ni][0] = f0[(size_t)t * CDIM + d0];
        r[ni][1] = f0[(size_t)t * CDIM + d0 + 64];
    }
    for (int c0 = 0; c0 < CDIM; c0 += 4) {
        float wo[4][2], wg[4][2];
#pragma unroll
        for (int cc = 0; cc < 4; ++cc) {
            wo[cc][0] = Wo0[(c0 + cc) * CDIM + d0];
            wo[cc][1] = Wo0[(c0 + cc) * CDIM + d0 + 64];
            wg[cc][0] = Wg[(c0 + cc) * CDIM + d0];
            wg[cc][1] = Wg[(c0 + cc) * CDIM + d0 + 64];
        }
#pragma unroll
        for (int ni = 0; ni < 2; ++ni) {
            int nn = g + ni * 4;
            float4 a = *(const float4*)&s_out0[nn][c0];
            float4 b2 = *(const float4*)&s_inv[nn][c0];
            r[ni][0] += a.x * wo[0][0] + a.y * wo[1][0] + a.z * wo[2][0] + a.w * wo[3][0]
                      + b2.x * wg[0][0] + b2.y * wg[1][0] + b2.z * wg[2][0] + b2.w * wg[3][0];
            r[ni][1] += a.x * wo[0][1] + a.y * wo[1][1] + a.z * wo[2][1] + a.w * wo[3][1]
                      + b2.x * wg[0][1] + b2.y * wg[1][1] + b2.z * wg[2][1] + b2.w * wg[3][1];
        }
    }
#pragma unroll
    for (int ni = 0; ni < 2; ++ni) {
        int t = t0 + g + ni * 4;
        f0out[(size_t)t * CDIM + d0] = r[ni][0];
        f0out[(size_t)t * CDIM + d0 + 64] = r[ni][1];
    }
}

// ---------------------------------------------------------------------------
// Kernel 7: masked mean pool per graph + linear head -> out [B,19]
// ---------------------------------------------------------------------------
__global__ __launch_bounds__(1024) void k_pool(const float* __restrict__ f0out,
                                               const int* __restrict__ starts,
                                               const int* __restrict__ counts,
                                               const float* __restrict__ headW,
                                               const float* __restrict__ headb,
                                               float* __restrict__ out) {
    __shared__ float part[8][CDIM];
    int b = blockIdx.x;
    int tid = threadIdx.x;
    int c = tid & 127;
    int slice = tid >> 7;  // 0..7
    int s = starts[b];
    int n = counts[b];

    float acc = 0.f;
    for (int i = slice; i < n; i += 8) {
        acc += f0out[(size_t)(s + i) * CDIM + c];
    }
    part[slice][c] = acc;
    __syncthreads();

    if (slice == 0) {
        float v = part[0][c] + part[1][c] + part[2][c] + part[3][c]
                + part[4][c] + part[5][c] + part[6][c] + part[7][c];
        part[0][c] = v / fmaxf((float)n, 1.f);  // pooled mean
    }
    __syncthreads();

    if (tid < 19 * 32) {
        int o = tid >> 5;
        int l = tid & 31;
        float p = 0.f;
#pragma unroll
        for (int cc = 0; cc < 4; ++cc) {
            int ch = l + cc * 32;
            p += part[0][ch] * headW[ch * 19 + o];
        }
        p += __shfl_xor(p, 16);
        p += __shfl_xor(p, 8);
        p += __shfl_xor(p, 4);
        p += __shfl_xor(p, 2);
        p += __shfl_xor(p, 1);
        if (l == 0) out[b * 19 + o] = p + headb[o];
    }
}

// ---------------------------------------------------------------------------
extern "C" void kernel_launch(void* const* d_in, const int* in_sizes, int n_in,
                              void* d_out, int out_size, void* d_ws, size_t ws_size,
                              hipStream_t stream) {
    const float* x    = (const float*)d_in[0];   // [T,11]
    const float* pos  = (const float*)d_in[1];   // [T,3]
    const int* batch  = (const int*)d_in[2];     // [T]
    const float* embW = (const float*)d_in[3];   // [11,128]
    const float* embb = (const float*)d_in[4];   // [128]
    const float* Wq   = (const float*)d_in[5];
    const float* Wk   = (const float*)d_in[6];
    const float* Wv0  = (const float*)d_in[7];
    const float* Wv1  = (const float*)d_in[8];
    const float* Wo0  = (const float*)d_in[9];
    const float* Wo1  = (const float*)d_in[10];
    const float* Wg   = (const float*)d_in[11];
    const float* dist_scale = (const float*)d_in[12];  // [4]
    const float* headW = (const float*)d_in[13];       // [128,19]
    const float* headb = (const float*)d_in[14];       // [19]
    float* out = (float*)d_out;                        // [16,19]

    char* w = (char*)d_ws;
    int* counts = (int*)w;
    int* starts = (int*)(w + 64);
    float* f0   = (float*)(w + 256);
    float* qkvv = f0 + (size_t)T_NODES * CDIM;
    int* nbr    = (int*)(qkvv + (size_t)T_NODES * 512);
    float4* dird = (float4*)(nbr + (size_t)T_NODES * KNN);          // [T][K] {dx,dy,dz,dist}
    float* out0 = (float*)(dird + (size_t)T_NODES * KNN);
    float* out1 = out0 + (size_t)T_NODES * CDIM;
    float* f0out = out1 + (size_t)T_NODES * CDIM * 3;

    k_counts<<<1, 256, 0, stream>>>(batch, starts, counts);
    k_embed<<<(T_NODES * CDIM) / 256, 256, 0, stream>>>(x, embW, embb, f0);
    k_knn<<<T_NODES / 4, 256, 0, stream>>>(pos, batch, starts, counts, nbr, dird);
    k_qkv<<<T_NODES / 16, 256, 0, stream>>>(f0, Wq, Wk, Wv0, Wv1, qkvv);
    k_attn<<<T_NODES / 2, 256, 0, stream>>>(qkvv, nbr, dird, dist_scale, out0, out1);
    k_mix<<<T_NODES / MIXN, 256, 0, stream>>>(f0, out0, out1, Wo1, Wo0, Wg, f0out);
    k_pool<<<BGRAPHS, 1024, 0, stream>>>(f0out, starts, counts, headW, headb, out);
}

// Round 7
// 144.580 us; speedup vs baseline: 1.1640x; 1.1640x over previous
//
#include <hip/hip_runtime.h>
#include <hip/hip_bf16.h>
#include <math.h>

#define T_NODES 8192
#define BGRAPHS 16
#define CDIM 128
#define HEADS 4
#define DHEAD 32
#define KNN 16

// ---------------------------------------------------------------------------
// Kernel 1: segment counts/starts from sorted batch ids
// ---------------------------------------------------------------------------
__global__ __launch_bounds__(256) void k_counts(const int* __restrict__ batch,
                                                int* __restrict__ starts,
                                                int* __restrict__ counts) {
    __shared__ int cnt[BGRAPHS];
    int tid = threadIdx.x;
    if (tid < BGRAPHS) cnt[tid] = 0;
    __syncthreads();
    for (int i = tid; i < T_NODES; i += 256) {
        atomicAdd(&cnt[batch[i]], 1);
    }
    __syncthreads();
    if (tid == 0) {
        int s = 0;
        for (int b = 0; b < BGRAPHS; ++b) {
            starts[b] = s;
            counts[b] = cnt[b];
            s += cnt[b];
        }
    }
}

// ---------------------------------------------------------------------------
// Kernel 2: node embedding f0 = x @ emb_W + emb_b   [T,128]
// ---------------------------------------------------------------------------
__global__ __launch_bounds__(256) void k_embed(const float* __restrict__ x,
                                               const float* __restrict__ embW,
                                               const float* __restrict__ embb,
                                               float* __restrict__ f0) {
    int gid = blockIdx.x * 256 + threadIdx.x;
    int t = gid >> 7;
    int c = gid & 127;
    float acc = embb[c];
#pragma unroll
    for (int i = 0; i < 11; ++i) {
        acc += x[t * 11 + i] * embW[i * CDIM + c];
    }
    f0[t * CDIM + c] = acc;
}

// ---------------------------------------------------------------------------
// Kernel 3: kNN. One wave (64 lanes) per node; lane holds 16 candidate slots
// (j = lane + sl*64, coalesced). Each lane Batcher-sorts its 16 (d2, slot)
// pairs once; then 16 rounds of {d2-only fmin wave reduce -> ballot winner ->
// winner shifts}. Writes packed dird float4 {dx,dy,dz,dist} per (t,k).
// ---------------------------------------------------------------------------
__global__ __launch_bounds__(256) void k_knn(const float* __restrict__ pos,
                                             const int* __restrict__ batch,
                                             const int* __restrict__ starts,
                                             const int* __restrict__ counts,
                                             int* __restrict__ nbr,
                                             float4* __restrict__ dird) {
    int wave = threadIdx.x >> 6;
    int lane = threadIdx.x & 63;
    int t = blockIdx.x * 4 + wave;
    if (t >= T_NODES) return;

    int b = batch[t];
    int s = starts[b];
    int n = counts[b];

    float px = pos[t * 3 + 0];
    float py = pos[t * 3 + 1];
    float pz = pos[t * 3 + 2];

    float sd[16];
    int ss[16];
#pragma unroll
    for (int sl = 0; sl < 16; ++sl) {
        int j = lane + sl * 64;
        float d2 = 1e30f;
        if (j < n) {
            int jj = s + j;
            float dx = px - pos[jj * 3 + 0];
            float dy = py - pos[jj * 3 + 1];
            float dz = pz - pos[jj * 3 + 2];
            d2 = dx * dx + dy * dy + dz * dz;
        }
        sd[sl] = d2;
        ss[sl] = sl;
    }

    // Batcher odd-even mergesort of 16 (d2, slot) pairs; ascending d2.
#pragma unroll
    for (int p = 1; p < 16; p <<= 1) {
#pragma unroll
        for (int k = p; k >= 1; k >>= 1) {
#pragma unroll
            for (int j = (k & (p - 1)); j + k < 16; j += 2 * k) {
#pragma unroll
                for (int i = 0; i < k; ++i) {
                    if (i + j + k < 16 && ((i + j) / (2 * p)) == ((i + j + k) / (2 * p))) {
                        int a = i + j, c2 = i + j + k;
                        bool sw = sd[a] > sd[c2];
                        float td = sd[a];
                        int ts = ss[a];
                        sd[a] = sw ? sd[c2] : sd[a];
                        ss[a] = sw ? ss[c2] : ss[a];
                        sd[c2] = sw ? td : sd[c2];
                        ss[c2] = sw ? ts : ss[c2];
                    }
                }
            }
        }
    }

    float resd = 1e30f;
    int resj = -1;

#pragma unroll
    for (int r = 0; r < KNN; ++r) {
        float rd = sd[0];
#pragma unroll
        for (int off = 32; off >= 1; off >>= 1) {
            rd = fminf(rd, __shfl_xor(rd, off));
        }
        unsigned long long mask = __ballot(sd[0] == rd);
        int wl = (int)__builtin_ctzll(mask);
        int ws = __shfl(ss[0], wl);
        if (lane == r) { resd = rd; resj = wl + ws * 64; }
        if (lane == wl) {
#pragma unroll
            for (int i = 0; i < 15; ++i) { sd[i] = sd[i + 1]; ss[i] = ss[i + 1]; }
            sd[15] = 1e30f;
        }
    }

    if (lane < KNN) {
        bool valid = (resd < 1e29f);
        int jf = valid ? (s + resj) : -1;
        nbr[t * KNN + lane] = jf;
        float dd = sqrtf(resd + 1e-6f);
        float dx = 0.f, dy = 0.f, dz = 0.f;
        if (valid) {
            float inv = 1.f / dd;
            dx = (px - pos[jf * 3 + 0]) * inv;
            dy = (py - pos[jf * 3 + 1]) * inv;
            dz = (pz - pos[jf * 3 + 2]) * inv;
        }
        float4 v;
        v.x = dx; v.y = dy; v.z = dz; v.w = dd;
        dird[t * KNN + lane] = v;
    }
}

// ---------------------------------------------------------------------------
// Kernel 4: fused QKV projection. qkvv[t, 0:512] = f0[t,:] @ [Wq|Wk|Wv0|Wv1]
// ---------------------------------------------------------------------------
__global__ __launch_bounds__(256) void k_qkv(const float* __restrict__ f0,
                                             const float* __restrict__ Wq,
                                             const float* __restrict__ Wk,
                                             const float* __restrict__ Wv0,
                                             const float* __restrict__ Wv1,
                                             float* __restrict__ qkvv) {
    __shared__ float sf[16][CDIM];
    int t0 = blockIdx.x * 16;
    int tid = threadIdx.x;
    for (int i = tid; i < 16 * CDIM; i += 256) {
        sf[i >> 7][i & 127] = f0[(t0 + (i >> 7)) * CDIM + (i & 127)];
    }
    __syncthreads();

    const float* W1 = (tid < 128) ? Wq : Wk;    // wave-uniform
    const float* W2 = (tid < 128) ? Wv0 : Wv1;  // wave-uniform
    int col = tid & 127;

    float acc1[16], acc2[16];
#pragma unroll
    for (int nn = 0; nn < 16; ++nn) { acc1[nn] = 0.f; acc2[nn] = 0.f; }

    for (int c0 = 0; c0 < CDIM; c0 += 8) {
        float w1[8], w2[8];
#pragma unroll
        for (int cc = 0; cc < 8; ++cc) {
            w1[cc] = W1[(c0 + cc) * CDIM + col];
            w2[cc] = W2[(c0 + cc) * CDIM + col];
        }
#pragma unroll
        for (int nn = 0; nn < 16; ++nn) {
            float4 fa = *(const float4*)&sf[nn][c0];
            float4 fb = *(const float4*)&sf[nn][c0 + 4];
            acc1[nn] += fa.x * w1[0] + fa.y * w1[1] + fa.z * w1[2] + fa.w * w1[3]
                      + fb.x * w1[4] + fb.y * w1[5] + fb.z * w1[6] + fb.w * w1[7];
            acc2[nn] += fa.x * w2[0] + fa.y * w2[1] + fa.z * w2[2] + fa.w * w2[3]
                      + fb.x * w2[4] + fb.y * w2[5] + fb.z * w2[6] + fb.w * w2[7];
        }
    }
#pragma unroll
    for (int nn = 0; nn < 16; ++nn) {
        qkvv[(size_t)(t0 + nn) * 512 + tid] = acc1[nn];
        qkvv[(size_t)(t0 + nn) * 512 + 256 + tid] = acc2[nn];
    }
}

// ---------------------------------------------------------------------------
// Kernel 5: kNN attention, one WAVE per node, two phases.
// Phase A: lane=(k,h): full 32-elem q.k dot in registers (no shuffles),
//          softmax over k via 4-stage shfl within 16-lane groups.
// Phase B: lane=channel-pair (2c,2c+1; same head): PV accumulate, float2
//          gather loads (coalesced 512B/inst per wave).
// 4 nodes per 256-thread block; XCD-swizzled for L2 locality of the gather.
// ---------------------------------------------------------------------------
__global__ __launch_bounds__(256) void k_attn(const float* __restrict__ qkvv,
                                              const int* __restrict__ nbr,
                                              const float4* __restrict__ dird,
                                              const float* __restrict__ dist_scale,
                                              float* __restrict__ out0,
                                              float* __restrict__ out1) {
    __shared__ float  s_a[4][64];   // [node][h*16+k]
    __shared__ float4 s_d[4][16];   // dird per node
    __shared__ int    s_j[4][16];   // neighbor ids

    int bid = blockIdx.x;
    // bijective XCD swizzle over 2048 blocks: 8 chunks x 256
    int swz = (bid & 7) * (T_NODES / 32) + (bid >> 3);
    int wave = threadIdx.x >> 6;
    int lane = threadIdx.x & 63;
    int t = swz * 4 + wave;

    // ---- Phase A: logits + softmax. lane = (k, h) ----
    int k = lane & 15;
    int h = lane >> 4;

    int j = nbr[t * KNN + k];
    float4 dv = dird[t * KNN + k];
    if (h == 0) { s_j[wave][k] = j; s_d[wave][k] = dv; }

    const float4* qv = (const float4*)&qkvv[(size_t)t * 512 + h * DHEAD];
    const float4* kv = (j >= 0) ? (const float4*)&qkvv[(size_t)j * 512 + 128 + h * DHEAD] : qv;
    float dot = 0.f;
#pragma unroll
    for (int i = 0; i < 8; ++i) {
        float4 a = qv[i], b2 = kv[i];
        dot += a.x * b2.x + a.y * b2.y + a.z * b2.z + a.w * b2.w;
    }
    float xs = dist_scale[h];
    float sp = (xs > 20.f) ? xs : log1pf(expf(xs));  // softplus
    float lg = (j >= 0) ? (dot * 0.17677669529663687f - sp * dv.w) : -1e30f;

    float m = lg;
    m = fmaxf(m, __shfl_xor(m, 1));
    m = fmaxf(m, __shfl_xor(m, 2));
    m = fmaxf(m, __shfl_xor(m, 4));
    m = fmaxf(m, __shfl_xor(m, 8));
    float e = expf(lg - m);
    float ssum = e;
    ssum += __shfl_xor(ssum, 1);
    ssum += __shfl_xor(ssum, 2);
    ssum += __shfl_xor(ssum, 4);
    ssum += __shfl_xor(ssum, 8);
    s_a[wave][h * 16 + k] = e / ssum;

    __syncthreads();

    // ---- Phase B: PV accumulate. lane handles channels 2*lane, 2*lane+1 ----
    int c2 = lane * 2;           // both channels share head hh
    int hh = lane >> 4;          // (2*lane)>>5

    float o0x = 0.f, o0y = 0.f;
    float o1xx = 0.f, o1xy = 0.f;
    float o1yx = 0.f, o1yy = 0.f;
    float o1zx = 0.f, o1zy = 0.f;

#pragma unroll
    for (int kk = 0; kk < KNN; ++kk) {
        int jj = s_j[wave][kk];
        if (jj >= 0) {
            float a = s_a[wave][hh * 16 + kk];
            float4 d = s_d[wave][kk];
            float2 v0 = *(const float2*)&qkvv[(size_t)jj * 512 + 256 + c2];
            float2 v1 = *(const float2*)&qkvv[(size_t)jj * 512 + 384 + c2];
            o0x += a * v0.x;
            o0y += a * v0.y;
            float w1x = a * v1.x, w1y = a * v1.y;
            o1xx += w1x * d.x; o1xy += w1y * d.x;
            o1yx += w1x * d.y; o1yy += w1y * d.y;
            o1zx += w1x * d.z; o1zy += w1y * d.z;
        }
    }

    float2 st;
    st.x = o0x; st.y = o0y;
    *(float2*)&out0[(size_t)t * CDIM + c2] = st;
    st.x = o1xx; st.y = o1xy;
    *(float2*)&out1[0 * (size_t)T_NODES * CDIM + (size_t)t * CDIM + c2] = st;
    st.x = o1yx; st.y = o1yy;
    *(float2*)&out1[1 * (size_t)T_NODES * CDIM + (size_t)t * CDIM + c2] = st;
    st.x = o1zx; st.y = o1zy;
    *(float2*)&out1[2 * (size_t)T_NODES * CDIM + (size_t)t * CDIM + c2] = st;
}

// ---------------------------------------------------------------------------
// Kernel 6: f1 = out1 @ Wo1 (per xyz), inv = ||f1||, f0_out = f0 + out0@Wo0 + inv@Wg
// LDS-staged, register-blocked. 8 nodes/block, 256 threads.
// ---------------------------------------------------------------------------
#define MIXN 8
__global__ __launch_bounds__(256) void k_mix(const float* __restrict__ f0,
                                             const float* __restrict__ out0,
                                             const float* __restrict__ out1,
                                             const float* __restrict__ Wo1,
                                             const float* __restrict__ Wo0,
                                             const float* __restrict__ Wg,
                                             float* __restrict__ f0out) {
    __shared__ float s_out1[3][MIXN][CDIM];  // 12 KB
    __shared__ float s_out0[MIXN][CDIM];     //  4 KB
    __shared__ float s_inv[MIXN][CDIM];      //  4 KB
    int tid = threadIdx.x;
    int t0 = blockIdx.x * MIXN;

    {
        const float4* p1 = (const float4*)out1;
        float4* s1 = (float4*)s_out1;
        for (int i = tid; i < 3 * MIXN * 32; i += 256) {
            int cp = i >> 8;
            int rem = i & 255;
            int nn = rem >> 5;
            int c4 = rem & 31;
            s1[i] = p1[(size_t)cp * (T_NODES * 32) + (size_t)(t0 + nn) * 32 + c4];
        }
        const float4* p0 = (const float4*)out0;
        float4* s0 = (float4*)s_out0;
        {
            int i = tid;
            int nn = i >> 5, c4 = i & 31;
            s0[i] = p0[(size_t)(t0 + nn) * 32 + c4];
        }
    }
    __syncthreads();

    int d0 = tid & 63;
    int g = tid >> 6;  // 0..3; nodes g and g+4

    float f1a[2][3][2];
#pragma unroll
    for (int ni = 0; ni < 2; ++ni)
#pragma unroll
        for (int cp = 0; cp < 3; ++cp) {
            f1a[ni][cp][0] = 0.f;
            f1a[ni][cp][1] = 0.f;
        }

    for (int c0 = 0; c0 < CDIM; c0 += 4) {
        float w[4][2];
#pragma unroll
        for (int cc = 0; cc < 4; ++cc) {
            w[cc][0] = Wo1[(c0 + cc) * CDIM + d0];
            w[cc][1] = Wo1[(c0 + cc) * CDIM + d0 + 64];
        }
#pragma unroll
        for (int ni = 0; ni < 2; ++ni) {
            int nn = g + ni * 4;
#pragma unroll
            for (int cp = 0; cp < 3; ++cp) {
                float4 v = *(const float4*)&s_out1[cp][nn][c0];
                f1a[ni][cp][0] += v.x * w[0][0] + v.y * w[1][0] + v.z * w[2][0] + v.w * w[3][0];
                f1a[ni][cp][1] += v.x * w[0][1] + v.y * w[1][1] + v.z * w[2][1] + v.w * w[3][1];
            }
        }
    }
#pragma unroll
    for (int ni = 0; ni < 2; ++ni) {
        int nn = g + ni * 4;
        s_inv[nn][d0] = sqrtf(f1a[ni][0][0] * f1a[ni][0][0] + f1a[ni][1][0] * f1a[ni][1][0]
                            + f1a[ni][2][0] * f1a[ni][2][0] + 1e-6f);
        s_inv[nn][d0 + 64] = sqrtf(f1a[ni][0][1] * f1a[ni][0][1] + f1a[ni][1][1] * f1a[ni][1][1]
                                 + f1a[ni][2][1] * f1a[ni][2][1] + 1e-6f);
    }
    __syncthreads();

    float r[2][2];
#pragma unroll
    for (int ni = 0; ni < 2; ++ni) {
        int t = t0 + g + ni * 4;
        r[ni][0] = f0[(size_t)t * CDIM + d0];
        r[ni][1] = f0[(size_t)t * CDIM + d0 + 64];
    }
    for (int c0 = 0; c0 < CDIM; c0 += 4) {
        float wo[4][2], wg[4][2];
#pragma unroll
        for (int cc = 0; cc < 4; ++cc) {
            wo[cc][0] = Wo0[(c0 + cc) * CDIM + d0];
            wo[cc][1] = Wo0[(c0 + cc) * CDIM + d0 + 64];
            wg[cc][0] = Wg[(c0 + cc) * CDIM + d0];
            wg[cc][1] = Wg[(c0 + cc) * CDIM + d0 + 64];
        }
#pragma unroll
        for (int ni = 0; ni < 2; ++ni) {
            int nn = g + ni * 4;
            float4 a = *(const float4*)&s_out0[nn][c0];
            float4 b2 = *(const float4*)&s_inv[nn][c0];
            r[ni][0] += a.x * wo[0][0] + a.y * wo[1][0] + a.z * wo[2][0] + a.w * wo[3][0]
                      + b2.x * wg[0][0] + b2.y * wg[1][0] + b2.z * wg[2][0] + b2.w * wg[3][0];
            r[ni][1] += a.x * wo[0][1] + a.y * wo[1][1] + a.z * wo[2][1] + a.w * wo[3][1]
                      + b2.x * wg[0][1] + b2.y * wg[1][1] + b2.z * wg[2][1] + b2.w * wg[3][1];
        }
    }
#pragma unroll
    for (int ni = 0; ni < 2; ++ni) {
        int t = t0 + g + ni * 4;
        f0out[(size_t)t * CDIM + d0] = r[ni][0];
        f0out[(size_t)t * CDIM + d0 + 64] = r[ni][1];
    }
}

// ---------------------------------------------------------------------------
// Kernel 7: masked mean pool per graph + linear head -> out [B,19]
// ---------------------------------------------------------------------------
__global__ __launch_bounds__(1024) void k_pool(const float* __restrict__ f0out,
                                               const int* __restrict__ starts,
                                               const int* __restrict__ counts,
                                               const float* __restrict__ headW,
                                               const float* __restrict__ headb,
                                               float* __restrict__ out) {
    __shared__ float part[8][CDIM];
    int b = blockIdx.x;
    int tid = threadIdx.x;
    int c = tid & 127;
    int slice = tid >> 7;  // 0..7
    int s = starts[b];
    int n = counts[b];

    float acc = 0.f;
    for (int i = slice; i < n; i += 8) {
        acc += f0out[(size_t)(s + i) * CDIM + c];
    }
    part[slice][c] = acc;
    __syncthreads();

    if (slice == 0) {
        float v = part[0][c] + part[1][c] + part[2][c] + part[3][c]
                + part[4][c] + part[5][c] + part[6][c] + part[7][c];
        part[0][c] = v / fmaxf((float)n, 1.f);  // pooled mean
    }
    __syncthreads();

    if (tid < 19 * 32) {
        int o = tid >> 5;
        int l = tid & 31;
        float p = 0.f;
#pragma unroll
        for (int cc = 0; cc < 4; ++cc) {
            int ch = l + cc * 32;
            p += part[0][ch] * headW[ch * 19 + o];
        }
        p += __shfl_xor(p, 16);
        p += __shfl_xor(p, 8);
        p += __shfl_xor(p, 4);
        p += __shfl_xor(p, 2);
        p += __shfl_xor(p, 1);
        if (l == 0) out[b * 19 + o] = p + headb[o];
    }
}

// ---------------------------------------------------------------------------
extern "C" void kernel_launch(void* const* d_in, const int* in_sizes, int n_in,
                              void* d_out, int out_size, void* d_ws, size_t ws_size,
                              hipStream_t stream) {
    const float* x    = (const float*)d_in[0];   // [T,11]
    const float* pos  = (const float*)d_in[1];   // [T,3]
    const int* batch  = (const int*)d_in[2];     // [T]
    const float* embW = (const float*)d_in[3];   // [11,128]
    const float* embb = (const float*)d_in[4];   // [128]
    const float* Wq   = (const float*)d_in[5];
    const float* Wk   = (const float*)d_in[6];
    const float* Wv0  = (const float*)d_in[7];
    const float* Wv1  = (const float*)d_in[8];
    const float* Wo0  = (const float*)d_in[9];
    const float* Wo1  = (const float*)d_in[10];
    const float* Wg   = (const float*)d_in[11];
    const float* dist_scale = (const float*)d_in[12];  // [4]
    const float* headW = (const float*)d_in[13];       // [128,19]
    const float* headb = (const float*)d_in[14];       // [19]
    float* out = (float*)d_out;                        // [16,19]

    char* w = (char*)d_ws;
    int* counts = (int*)w;
    int* starts = (int*)(w + 64);
    float* f0   = (float*)(w + 256);
    float* qkvv = f0 + (size_t)T_NODES * CDIM;
    int* nbr    = (int*)(qkvv + (size_t)T_NODES * 512);
    float4* dird = (float4*)(nbr + (size_t)T_NODES * KNN);          // [T][K] {dx,dy,dz,dist}
    float* out0 = (float*)(dird + (size_t)T_NODES * KNN);
    float* out1 = out0 + (size_t)T_NODES * CDIM;
    float* f0out = out1 + (size_t)T_NODES * CDIM * 3;

    k_counts<<<1, 256, 0, stream>>>(batch, starts, counts);
    k_embed<<<(T_NODES * CDIM) / 256, 256, 0, stream>>>(x, embW, embb, f0);
    k_knn<<<T_NODES / 4, 256, 0, stream>>>(pos, batch, starts, counts, nbr, dird);
    k_qkv<<<T_NODES / 16, 256, 0, stream>>>(f0, Wq, Wk, Wv0, Wv1, qkvv);
    k_attn<<<T_NODES / 4, 256, 0, stream>>>(qkvv, nbr, dird, dist_scale, out0, out1);
    k_mix<<<T_NODES / MIXN, 256, 0, stream>>>(f0, out0, out1, Wo1, Wo0, Wg, f0out);
    k_pool<<<BGRAPHS, 1024, 0, stream>>>(f0out, starts, counts, headW, headb, out);
}